// Round 11
// baseline (268.115 us; speedup 1.0000x reference)
//
#include <hip/hip_runtime.h>
#include <hip/hip_bf16.h>
#include <math.h>

#define NN 16384
#define BB 64
#define NPG 256
#define KNN 100
#define FIN 5
#define HH 128
#define H2 768
#define SLOPE 0.01f

typedef __bf16 bf16x8 __attribute__((ext_vector_type(8)));
typedef float f32x4 __attribute__((ext_vector_type(4)));

// Inputs are fp32 (verified R3). Dtype detect inline: bn_gamma all-ones -> first 32 bits
// 0x3F800000 (fp32) vs 0x3F803F80 (bf16).
__device__ __forceinline__ int detect_bf(const void* gamma) {
    return ((const unsigned*)gamma)[0] == 0x3F803F80u;
}
__device__ __forceinline__ float loadin(const void* p, size_t i, int bf) {
    return bf ? __bfloat162float(((const __hip_bfloat16*)p)[i]) : ((const float*)p)[i];
}
template <typename T>
__device__ __forceinline__ float ldT(const T* p, size_t i) { return (float)p[i]; }
template <>
__device__ __forceinline__ float ldT<__hip_bfloat16>(const __hip_bfloat16* p, size_t i) {
    return __bfloat162float(p[i]);
}
__device__ __forceinline__ float4 ldT4(const float* p) { return *(const float4*)p; }
__device__ __forceinline__ float4 ldT4(const __hip_bfloat16* p) {
    ushort4 u = *(const ushort4*)p;
    return make_float4(__uint_as_float((unsigned)u.x << 16),
                       __uint_as_float((unsigned)u.y << 16),
                       __uint_as_float((unsigned)u.z << 16),
                       __uint_as_float((unsigned)u.w << 16));
}
__device__ __forceinline__ void stage_chunk(float* dst, const float* src, int n, int t) {
    const float4* s = (const float4*)src;
    float4* d = (float4*)dst;
    int n4 = n >> 2;
    for (int i = t; i < n4; i += 256) d[i] = s[i];
}
__device__ __forceinline__ void stage_chunk(float* dst, const __hip_bfloat16* src, int n, int t) {
    const ushort4* s = (const ushort4*)src;
    int n4 = n >> 2;
    for (int i = t; i < n4; i += 256) {
        ushort4 u = s[i];
        dst[i * 4 + 0] = __uint_as_float((unsigned)u.x << 16);
        dst[i * 4 + 1] = __uint_as_float((unsigned)u.y << 16);
        dst[i * 4 + 2] = __uint_as_float((unsigned)u.z << 16);
        dst[i * 4 + 3] = __uint_as_float((unsigned)u.w << 16);
    }
}

// Order-preserving fp32 <-> u32 map for atomicMax-based max pooling.
__device__ __forceinline__ unsigned enc_f(float f) {
    unsigned u = __float_as_uint(f);
    return (u & 0x80000000u) ? ~u : (u | 0x80000000u);
}
__device__ __forceinline__ float dec_f(unsigned u) {
    return __uint_as_float((u & 0x80000000u) ? (u & 0x7FFFFFFFu) : ~u);
}
// fp32 -> bf16 bits, round-to-nearest-even (finite values only)
__device__ __forceinline__ unsigned f2bf(float f) {
    unsigned u = __float_as_uint(f);
    unsigned r = 0x7fffu + ((u >> 16) & 1u);
    return (u + r) >> 16;
}
// split fp32 -> (hi = truncated bf16 bits [exact], lo = bf16(x - hi))
__device__ __forceinline__ void split1(float x, unsigned short& h, unsigned short& l) {
    unsigned u = __float_as_uint(x);
    unsigned hb = u & 0xFFFF0000u;
    h = (unsigned short)(hb >> 16);
    float rem = x - __uint_as_float(hb);     // exact in fp32
    l = (unsigned short)f2bf(rem);
}
// expand 8 adjacency bits -> bf16x8 frag of {0,1}: element j = bit j (k-order)
__device__ __forceinline__ bf16x8 expand_bits(unsigned bits) {
    uint4 aw;
    aw.x = ((bits & 1u)   ? 0x3F80u : 0u) | ((bits & 2u)   ? 0x3F800000u : 0u);
    aw.y = ((bits & 4u)   ? 0x3F80u : 0u) | ((bits & 8u)   ? 0x3F800000u : 0u);
    aw.z = ((bits & 16u)  ? 0x3F80u : 0u) | ((bits & 32u)  ? 0x3F800000u : 0u);
    aw.w = ((bits & 64u)  ? 0x3F80u : 0u) | ((bits & 128u) ? 0x3F800000u : 0u);
    return *(bf16x8*)&aw;
}

// ---------------- KNN v7: radix-select top-100 (no sort, no LDS shuffles) ----------------
__global__ __launch_bounds__(256) void knn_kernel(const void* __restrict__ x_in,
                                                  const void* gamma,
                                                  unsigned char* __restrict__ nbr,
                                                  float* __restrict__ g,
                                                  float* __restrict__ outf,
                                                  unsigned* __restrict__ done) {
    int blk = blockIdx.x;
    int bf = detect_bf(gamma);
    int b = blk >> 6;
    int wave = threadIdx.x >> 6;
    int lane = threadIdx.x & 63;
    int il = ((blk & 63) << 2) + wave;
    {
        int gi = blk * 256 + threadIdx.x;
        if (blk < 192 && gi < BB * H2) {
            int cm = gi & 255;
            g[gi] = (cm < 128) ? 0.0f : __uint_as_float(0x007FFFFFu);
        }
        if (blk == 0 && threadIdx.x < BB) {
            outf[threadIdx.x] = 0.0f;
            done[threadIdx.x] = 0u;
        }
    }
    __shared__ float xg[FIN * NPG];   // transposed: xg[c*256 + node]
    for (int idx = threadIdx.x; idx < NPG * FIN; idx += 256) {
        int node = idx / FIN, c = idx - node * FIN;
        xg[c * NPG + node] = loadin(x_in, (size_t)b * NPG * FIN + idx, bf);
    }
    __syncthreads();
    float dq[4] = {0.f, 0.f, 0.f, 0.f};
    #pragma unroll
    for (int c = 0; c < FIN; ++c) {
        float xi = xg[c * NPG + il];                          // broadcast
        float4 xv = *(const float4*)&xg[c * NPG + lane * 4];  // conflict-free b128
        float d0 = xi - xv.x, d1 = xi - xv.y, d2 = xi - xv.z, d3 = xi - xv.w;
        dq[0] += d0 * d0; dq[1] += d1 * d1; dq[2] += d2 * d2; dq[3] += d3 * d3;
    }
    // keys: u32 distance bits (all positive -> uint order == float order); self = huge
    unsigned dk[4];
    #pragma unroll
    for (int q = 0; q < 4; ++q) {
        int e = lane * 4 + q;
        float dd = (e == il) ? 1e30f : dq[q];
        dk[q] = __float_as_uint(dd);
    }
    // binary search for T = 100th smallest value: max P with count(d < P) < 100
    unsigned P = 0;
    for (int bit = 30; bit >= 0; --bit) {
        unsigned cand = P | (1u << bit);
        int c = __popcll(__ballot(dk[0] < cand)) + __popcll(__ballot(dk[1] < cand))
              + __popcll(__ballot(dk[2] < cand)) + __popcll(__ballot(dk[3] < cand));
        if (c < KNN) P = cand;
    }
    // selection: all d<T, plus (KNN - n_less) of d==T by smallest index e=lane*4+q
    unsigned long long meq[4];
    int n_less = 0;
    #pragma unroll
    for (int q = 0; q < 4; ++q) {
        n_less += __popcll(__ballot(dk[q] < P));
        meq[q] = __ballot(dk[q] == P);
    }
    int quota = KNN - n_less;
    unsigned long long below = (1ull << lane) - 1ull;
    int run_eq = __popcll(meq[0] & below) + __popcll(meq[1] & below)
               + __popcll(meq[2] & below) + __popcll(meq[3] & below);
    bool sel[4];
    #pragma unroll
    for (int q = 0; q < 4; ++q) {
        int iseq = (int)((meq[q] >> lane) & 1ull);
        sel[q] = (dk[q] < P) || (iseq && run_eq < quota);
        run_eq += iseq;
    }
    unsigned long long msel[4];
    #pragma unroll
    for (int q = 0; q < 4; ++q) msel[q] = __ballot(sel[q]);
    int pos = __popcll(msel[0] & below) + __popcll(msel[1] & below)
            + __popcll(msel[2] & below) + __popcll(msel[3] & below);
    unsigned char* nb = &nbr[(size_t)(b * NPG + il) * KNN];
    #pragma unroll
    for (int q = 0; q < 4; ++q) {
        if (sel[q]) nb[pos] = (unsigned char)(lane * 4 + q);
        pos += sel[q] ? 1 : 0;
    }
}

// ---------------- aggregation, C=5, BOTH hops fused (x converted inline) ----------------
__global__ void agg5x2_kernel(const void* __restrict__ x_in, const void* gamma,
                              const unsigned char* __restrict__ nbr,
                              float* __restrict__ t5a, float* __restrict__ t5b, float nrm) {
    int b = blockIdx.x, i = threadIdx.x;
    int bf = detect_bf(gamma);
    __shared__ float xs[NPG * FIN];
    __shared__ float ys[NPG * FIN];
    for (int idx = threadIdx.x; idx < NPG * FIN; idx += 256)
        xs[idx] = loadin(x_in, (size_t)b * NPG * FIN + idx, bf);
    __syncthreads();
    const unsigned char* nb = nbr + (size_t)(b * NPG + i) * KNN;
    float a0=0.f, a1=0.f, a2=0.f, a3=0.f, a4=0.f;
    for (int k = 0; k < KNN; ++k) {
        int base = (int)nb[k] * FIN;
        a0 += xs[base+0]; a1 += xs[base+1]; a2 += xs[base+2];
        a3 += xs[base+3]; a4 += xs[base+4];
    }
    a0 *= nrm; a1 *= nrm; a2 *= nrm; a3 *= nrm; a4 *= nrm;
    size_t o = (size_t)(b * NPG + i) * FIN;
    t5a[o+0] = a0; t5a[o+1] = a1; t5a[o+2] = a2; t5a[o+3] = a3; t5a[o+4] = a4;
    ys[i*FIN+0] = a0; ys[i*FIN+1] = a1; ys[i*FIN+2] = a2;
    ys[i*FIN+3] = a3; ys[i*FIN+4] = a4;
    __syncthreads();
    a0=0.f; a1=0.f; a2=0.f; a3=0.f; a4=0.f;
    for (int k = 0; k < KNN; ++k) {
        int base = (int)nb[k] * FIN;
        a0 += ys[base+0]; a1 += ys[base+1]; a2 += ys[base+2];
        a3 += ys[base+3]; a4 += ys[base+4];
    }
    t5b[o+0] = nrm*a0; t5b[o+1] = nrm*a1; t5b[o+2] = nrm*a2;
    t5b[o+3] = nrm*a3; t5b[o+4] = nrm*a4;
}

// ---------------- aggregation, C=128, BOTH hops, MFMA + bitmask adjacency ----------------
// One block = (graph, 32-ch slice), all 256 rows. Adjacency as bitmask (thread t = row t,
// 8 u32, LDS stride 9 -> conflict-free). A-fragments expanded on the fly (8 bits ->
// bf16x8 {0,1.0}); frag/swizzle layout identical to the verified agg_mfma. Hop1 acc fp32
// -> global (tagmm input) + f2bf(nrm*acc) -> H1t (bit-identical to the 2-launch path:
// same MFMA k-order, same f2bf of the same value); hop2 reads H1t after one sync.
__global__ __launch_bounds__(256) void agg2_mfma_kernel(
        const float* __restrict__ hin, const unsigned char* __restrict__ nbr,
        float* __restrict__ hout1, float* __restrict__ hout2, float nrm) {
    __shared__ unsigned Abits[256 * 9];                     // 9 KB (stride 9: bank-spread)
    __shared__ __align__(16) unsigned short Ht[32 * 256];   // 16 KB
    __shared__ __align__(16) unsigned short H1t[32 * 256];  // 16 KB
    int t = threadIdx.x;
    int gph = blockIdx.x;
    int c0 = blockIdx.y * 32;
    // adjacency bitmask: thread t owns row t
    {
        unsigned m[8] = {0u,0u,0u,0u,0u,0u,0u,0u};
        const unsigned char* nb = nbr + ((size_t)(gph * NPG + t)) * KNN;
        #pragma unroll 5
        for (int k4 = 0; k4 < KNN / 4; ++k4) {
            uchar4 n4 = *(const uchar4*)&nb[k4 * 4];
            m[n4.x >> 5] |= 1u << (n4.x & 31);
            m[n4.y >> 5] |= 1u << (n4.y & 31);
            m[n4.z >> 5] |= 1u << (n4.z & 31);
            m[n4.w >> 5] |= 1u << (n4.w & 31);
        }
        #pragma unroll
        for (int w = 0; w < 8; ++w) Abits[t * 9 + w] = m[w];
    }
    // stage Ht [32ch][256node] bf16, swizzled, 4-node packed b64 writes
    for (int it = t; it < NPG * 2; it += 256) {   // nq = it>>3 (0..63), c4 = it&7
        int nq = it >> 3, c4 = it & 7;
        const float* src = &hin[((size_t)(gph * NPG + nq * 4)) * HH + c0 + c4 * 4];
        float4 v0 = *(const float4*)(src);
        float4 v1 = *(const float4*)(src + HH);
        float4 v2 = *(const float4*)(src + 2 * HH);
        float4 v3 = *(const float4*)(src + 3 * HH);
        #pragma unroll
        for (int j = 0; j < 4; ++j) {
            int c = c4 * 4 + j;
            ushort4 pk;
            pk.x = (unsigned short)f2bf((&v0.x)[j]);
            pk.y = (unsigned short)f2bf((&v1.x)[j]);
            pk.z = (unsigned short)f2bf((&v2.x)[j]);
            pk.w = (unsigned short)f2bf((&v3.x)[j]);
            unsigned off = (unsigned)((c * 512 + nq * 8) ^ ((c & 7) << 4));
            *(ushort4*)((char*)Ht + off) = pk;
        }
    }
    __syncthreads();
    int wv = t >> 6, lane = t & 63;
    int kgrp = lane >> 4;                        // k-group 0..3 (8 k each)
    unsigned kgb = (unsigned)(kgrp * 16);        // byte offset in 512B Ht row
    unsigned swz = (unsigned)((lane & 7) << 4);
    #pragma unroll
    for (int hop = 0; hop < 2; ++hop) {
        const unsigned short* Bsrc = hop ? H1t : Ht;
        float* gout = hop ? hout2 : hout1;
        #pragma unroll
        for (int mt = 0; mt < 4; ++mt) {
            int rbase = wv * 64 + mt * 16;
            int arow = rbase + (lane & 15);
            f32x4 acc0 = (f32x4){0.f, 0.f, 0.f, 0.f};
            f32x4 acc1 = (f32x4){0.f, 0.f, 0.f, 0.f};
            #pragma unroll
            for (int ks = 0; ks < 8; ++ks) {
                unsigned bits = (Abits[arow * 9 + ks] >> (kgrp * 8)) & 0xFFu;
                bf16x8 a = expand_bits(bits);
                unsigned b0 = ((unsigned)((lane & 15) * 512) + kgb + ks * 64) ^ swz;
                unsigned b1 = ((unsigned)((16 + (lane & 15)) * 512) + kgb + ks * 64) ^ swz;
                bf16x8 bv0 = *(const bf16x8*)((char*)Bsrc + b0);
                bf16x8 bv1 = *(const bf16x8*)((char*)Bsrc + b1);
                acc0 = __builtin_amdgcn_mfma_f32_16x16x32_bf16(a, bv0, acc0, 0, 0, 0);
                acc1 = __builtin_amdgcn_mfma_f32_16x16x32_bf16(a, bv1, acc1, 0, 0, 0);
            }
            int drow = rbase + (lane >> 4) * 4;
            #pragma unroll
            for (int nt = 0; nt < 2; ++nt) {
                const f32x4& av = nt ? acc1 : acc0;
                int ch = nt * 16 + (lane & 15);
                #pragma unroll
                for (int reg = 0; reg < 4; ++reg) {
                    float v = av[reg] * nrm;
                    gout[((size_t)(gph * NPG + drow + reg)) * HH + c0 + ch] = v;
                    if (hop == 0) {
                        unsigned off = ((unsigned)(ch * 512 + (drow + reg) * 2))
                                     ^ ((unsigned)((ch & 7) << 4));
                        *(unsigned short*)((char*)H1t + off) = (unsigned short)f2bf(v);
                    }
                }
            }
        }
        __syncthreads();   // H1t complete before hop2 reads it
    }
}

// ---------------- pool epilogue (16-lane-group layout, used by tagmm5) ----------------
__device__ __forceinline__ void pool_epilogue(float* g, int b, int gc0, int cg, int rp,
                                              float* sv, float* mv) {
    #pragma unroll
    for (int mask = 1; mask < 16; mask <<= 1) {
        #pragma unroll
        for (int i = 0; i < 8; ++i) {
            sv[i] += __shfl_xor(sv[i], mask);
            mv[i] = fmaxf(mv[i], __shfl_xor(mv[i], mask));
        }
    }
    if (rp == 0) {
        #pragma unroll
        for (int i = 0; i < 8; ++i) {
            atomicAdd(&g[(size_t)b * H2 + gc0 + cg * 8 + i], sv[i]);
            atomicMax((unsigned*)&g[(size_t)b * H2 + gc0 + HH + cg * 8 + i], enc_f(mv[i]));
        }
    }
}

// ---------------- tagmm5 (+fused pool), X0 converted inline from raw x ----------------
template <typename T>
__device__ __forceinline__ void tagmm5_body(
        const T* __restrict__ X0raw, const float* __restrict__ X1,
        const float* __restrict__ X2,
        const T* __restrict__ W, const T* __restrict__ bias,
        float* __restrict__ O, float* g, float* Ws, float* Xs) {
    int t = threadIdx.x;
    int r0 = blockIdx.x * 16;
    int r = t & 15, cg = t >> 4;
    float acc[8] = {0.f,0.f,0.f,0.f,0.f,0.f,0.f,0.f};
    for (int h = 0; h < 3; ++h) {
        stage_chunk(Ws, W + (size_t)h * FIN * HH, FIN * HH, t);
        for (int idx = t; idx < 16 * FIN; idx += 256) {
            int rr = idx / FIN, k = idx - rr * FIN;
            size_t src = (size_t)(r0 + rr) * FIN + k;
            Xs[rr * 9 + k] = (h == 0) ? ldT(X0raw, src)
                           : (h == 1) ? X1[src] : X2[src];
        }
        __syncthreads();
        #pragma unroll
        for (int k = 0; k < FIN; ++k) {
            float xv = Xs[r * 9 + k];
            const float4 wa = *(const float4*)&Ws[k * HH + cg * 8];
            const float4 wb = *(const float4*)&Ws[k * HH + cg * 8 + 4];
            acc[0] += xv * wa.x; acc[1] += xv * wa.y;
            acc[2] += xv * wa.z; acc[3] += xv * wa.w;
            acc[4] += xv * wb.x; acc[5] += xv * wb.y;
            acc[6] += xv * wb.z; acc[7] += xv * wb.w;
        }
        __syncthreads();
    }
    size_t orow = (size_t)(r0 + r) * HH + cg * 8;
    float sv[8], mv[8];
    #pragma unroll
    for (int m = 0; m < 8; ++m) {
        float v = acc[m] + ldT(bias, cg * 8 + m);
        v = v > 0.f ? v : SLOPE * v;
        O[orow + m] = v;
        sv[m] = v * (1.0f / NPG);
        mv[m] = v;
    }
    pool_epilogue(g, r0 >> 8, 0, cg, r, sv, mv);
}

__global__ __launch_bounds__(256) void tagmm5_kernel(
        const void* X0raw, const float* X1, const float* X2,
        const void* W, const void* bias, float* O, float* g, const void* gamma) {
    __shared__ float Ws[FIN * HH];
    __shared__ float Xs[16 * 9];
    if (detect_bf(gamma))
        tagmm5_body<__hip_bfloat16>((const __hip_bfloat16*)X0raw, X1, X2,
                                    (const __hip_bfloat16*)W,
                                    (const __hip_bfloat16*)bias, O, g, Ws, Xs);
    else
        tagmm5_body<float>((const float*)X0raw, X1, X2, (const float*)W,
                           (const float*)bias, O, g, Ws, Xs);
}

// ---------------- tagmm128 via MFMA, 3-pass split-bf16 (+fused pool) ----------------
template <typename T>
__device__ __forceinline__ void tagmm_mfma_body(
        const float* __restrict__ X0, const float* __restrict__ X1,
        const float* __restrict__ X2,
        const T* __restrict__ W, const T* __restrict__ bias,
        float* __restrict__ O, float* g, int gcp,
        unsigned short* Xhi, unsigned short* Xlo,
        unsigned short* Whi, unsigned short* Wlo, float* pred) {
    int t = threadIdx.x;
    int m0 = blockIdx.x * 64;
    int gc0 = blockIdx.y * 64;
    int wv = t >> 6, lane = t & 63;
    const float* Xh[3] = {X0, X1, X2};
    f32x4 acc[4];
    #pragma unroll
    for (int nt = 0; nt < 4; ++nt) acc[nt] = (f32x4){0.f, 0.f, 0.f, 0.f};
    unsigned kgb = (unsigned)((lane >> 4) * 16);
    unsigned swz = (unsigned)((lane & 7) << 4);
    unsigned abase = (unsigned)((wv * 16 + (lane & 15)) * 256) + kgb;
    for (int h = 0; h < 3; ++h) {
        const float* X = Xh[h];
        for (int i = t; i < 2048; i += 256) {
            int row = i >> 5, c4 = i & 31;
            float4 v = *(const float4*)&X[(size_t)(m0 + row) * HH + c4 * 4];
            unsigned off = (unsigned)((row * 256 + c4 * 8) ^ ((row & 7) << 4));
            ushort4 h4, l4;
            split1(v.x, h4.x, l4.x); split1(v.y, h4.y, l4.y);
            split1(v.z, h4.z, l4.z); split1(v.w, h4.w, l4.w);
            *(ushort4*)((char*)Xhi + off) = h4;
            *(ushort4*)((char*)Xlo + off) = l4;
        }
        const T* Wg = W + ((size_t)h * HH) * HH + gc0;
        for (int i = t; i < 512; i += 256) {      // kq = i>>4 (0..31), n4 = i&15
            int kq = i >> 4, n4 = i & 15;
            int k0 = kq * 4;
            float4 v0 = ldT4(Wg + (size_t)(k0 + 0) * HH + n4 * 4);
            float4 v1 = ldT4(Wg + (size_t)(k0 + 1) * HH + n4 * 4);
            float4 v2 = ldT4(Wg + (size_t)(k0 + 2) * HH + n4 * 4);
            float4 v3 = ldT4(Wg + (size_t)(k0 + 3) * HH + n4 * 4);
            #pragma unroll
            for (int j = 0; j < 4; ++j) {
                int n = n4 * 4 + j;
                ushort4 hv, lv;
                split1((&v0.x)[j], hv.x, lv.x);
                split1((&v1.x)[j], hv.y, lv.y);
                split1((&v2.x)[j], hv.z, lv.z);
                split1((&v3.x)[j], hv.w, lv.w);
                unsigned off = (unsigned)((n * 256 + k0 * 2) ^ ((n & 7) << 4));
                *(ushort4*)((char*)Whi + off) = hv;
                *(ushort4*)((char*)Wlo + off) = lv;
            }
        }
        __syncthreads();
        #pragma unroll
        for (int ks = 0; ks < 4; ++ks) {
            bf16x8 ah = *(const bf16x8*)((char*)Xhi + ((abase + ks * 64) ^ swz));
            bf16x8 al = *(const bf16x8*)((char*)Xlo + ((abase + ks * 64) ^ swz));
            #pragma unroll
            for (int nt = 0; nt < 4; ++nt) {
                unsigned bb = ((unsigned)((nt * 16 + (lane & 15)) * 256) + kgb + ks * 64) ^ swz;
                bf16x8 bh = *(const bf16x8*)((char*)Whi + bb);
                bf16x8 bl = *(const bf16x8*)((char*)Wlo + bb);
                acc[nt] = __builtin_amdgcn_mfma_f32_16x16x32_bf16(ah, bh, acc[nt], 0, 0, 0);
                acc[nt] = __builtin_amdgcn_mfma_f32_16x16x32_bf16(ah, bl, acc[nt], 0, 0, 0);
                acc[nt] = __builtin_amdgcn_mfma_f32_16x16x32_bf16(al, bh, acc[nt], 0, 0, 0);
            }
        }
        __syncthreads();
    }
    int b = m0 >> 8;
    int grow0 = m0 + wv * 16 + (lane >> 4) * 4;
    float* psum = pred;            // [4][64]
    float* pmax = pred + 256;      // [4][64]
    #pragma unroll
    for (int nt = 0; nt < 4; ++nt) {
        int ncol = nt * 16 + (lane & 15);
        float bv = ldT(bias, gc0 + ncol);
        float cs = 0.f, cm = -INFINITY;
        #pragma unroll
        for (int reg = 0; reg < 4; ++reg) {
            float v = acc[nt][reg] + bv;
            v = v > 0.f ? v : SLOPE * v;
            O[(size_t)(grow0 + reg) * HH + gc0 + ncol] = v;
            cs += v;
            cm = fmaxf(cm, v);
        }
        cs += __shfl_xor(cs, 16); cs += __shfl_xor(cs, 32);
        cm = fmaxf(cm, __shfl_xor(cm, 16)); cm = fmaxf(cm, __shfl_xor(cm, 32));
        if (lane < 16) {
            psum[wv * 64 + ncol] = cs;
            pmax[wv * 64 + ncol] = cm;
        }
    }
    __syncthreads();
    if (t < 64) {
        float s = psum[t] + psum[64 + t] + psum[128 + t] + psum[192 + t];
        float m = fmaxf(fmaxf(pmax[t], pmax[64 + t]), fmaxf(pmax[128 + t], pmax[192 + t]));
        atomicAdd(&g[(size_t)b * H2 + gcp + gc0 + t], s * (1.0f / NPG));
        atomicMax((unsigned*)&g[(size_t)b * H2 + gcp + HH + gc0 + t], enc_f(m));
    }
}

__global__ __launch_bounds__(256) void tagmm_mfma_kernel(
        const float* X0, const float* X1, const float* X2,
        const void* W, const void* bias, float* O, float* g, int gcp, const void* gamma) {
    __shared__ __align__(16) unsigned short Xhi[64 * 128];  // 16 KB
    __shared__ __align__(16) unsigned short Xlo[64 * 128];
    __shared__ __align__(16) unsigned short Whi[64 * 128];  // [n][k]
    __shared__ __align__(16) unsigned short Wlo[64 * 128];
    __shared__ float pred[512];                             // psum[4][64] + pmax[4][64]
    if (detect_bf(gamma))
        tagmm_mfma_body<__hip_bfloat16>(X0, X1, X2, (const __hip_bfloat16*)W,
                                        (const __hip_bfloat16*)bias, O, g, gcp,
                                        Xhi, Xlo, Whi, Wlo, pred);
    else
        tagmm_mfma_body<float>(X0, X1, X2, (const float*)W, (const float*)bias,
                               O, g, gcp, Xhi, Xlo, Whi, Wlo, pred);
}

// ---------------- batchnorm: one-pass sum/sumsq; writes SPLIT (hi,lo) output ----------
__global__ void bn_split_kernel(const float* __restrict__ g, const void* gamma,
                                const void* beta, unsigned short* __restrict__ ghi,
                                unsigned short* __restrict__ glo) {
    int c = blockIdx.x * 128 + threadIdx.x;
    int bf = detect_bf(gamma);
    int ismax = (c & 255) >= 128;
    float s = 0.f, s2 = 0.f;
    #pragma unroll 8
    for (int b = 0; b < BB; ++b) {
        float raw = g[(size_t)b * H2 + c];
        float x = ismax ? dec_f(__float_as_uint(raw)) : raw;
        s += x; s2 += x * x;
    }
    float mu = s * (1.0f / BB);
    float var = fmaxf(s2 * (1.0f / BB) - mu * mu, 0.f);
    float rs = 1.0f / sqrtf(var + 1e-5f);
    float ga = loadin(gamma, c, bf), be = loadin(beta, c, bf);
    #pragma unroll 8
    for (int b = 0; b < BB; ++b) {
        float raw = g[(size_t)b * H2 + c];
        float x = ismax ? dec_f(__float_as_uint(raw)) : raw;
        float y = (x - mu) * rs * ga + be;
        unsigned short h, l;
        split1(y, h, l);
        ghi[(size_t)b * H2 + c] = h;
        glo[(size_t)b * H2 + c] = l;
    }
}

// ---------------- MLP layer via MFMA, persistent split-bf16 activations ----------------
template <typename T>
__device__ __forceinline__ void mlp_mfma2_body(
        const unsigned short* __restrict__ Xhi_g, const unsigned short* __restrict__ Xlo_g,
        const T* __restrict__ W, const T* __restrict__ bias,
        unsigned short* __restrict__ Ohi, unsigned short* __restrict__ Olo,
        const T* __restrict__ ow, const T* __restrict__ ob,
        float* __restrict__ outf, unsigned* __restrict__ done, void* out, int bf,
        unsigned short* Xhi, unsigned short* Xlo,
        unsigned short* Whi, unsigned short* Wlo, float* red4, float* red) {
    int t = threadIdx.x;
    int col0 = blockIdx.x * 16;
    int wv = t >> 6, lane = t & 63;
    f32x4 acc[4];
    #pragma unroll
    for (int mt = 0; mt < 4; ++mt) acc[mt] = (f32x4){0.f, 0.f, 0.f, 0.f};
    unsigned swz = (unsigned)((lane & 7) << 4);
    unsigned kgb = (unsigned)(wv * 64 + (lane >> 4) * 16);   // wave k-slice in 256B row
    for (int ch = 0; ch < 6; ++ch) {
        int k0 = ch * 128;
        // stage X chunk: pure b128 copies (global pre-split, same [row][k] layout)
        #pragma unroll
        for (int u = 0; u < 4; ++u) {
            int i = t + u * 256;
            int row = i >> 4, grp = i & 15;
            uint4 vh = *(const uint4*)&Xhi_g[(size_t)row * H2 + k0 + grp * 8];
            uint4 vl = *(const uint4*)&Xlo_g[(size_t)row * H2 + k0 + grp * 8];
            unsigned off = (unsigned)((row * 256 + grp * 16) ^ ((row & 7) << 4));
            *(uint4*)((char*)Xhi + off) = vh;
            *(uint4*)((char*)Xlo + off) = vl;
        }
        // stage W chunk transposed+split: [n][k], 128 items (kq x n4), 4-k packed b64
        if (t < 128) {
            int kq = t >> 2, n4 = t & 3;
            int kb = k0 + kq * 4;
            float4 v0 = ldT4(W + (size_t)(kb + 0) * H2 + col0 + n4 * 4);
            float4 v1 = ldT4(W + (size_t)(kb + 1) * H2 + col0 + n4 * 4);
            float4 v2 = ldT4(W + (size_t)(kb + 2) * H2 + col0 + n4 * 4);
            float4 v3 = ldT4(W + (size_t)(kb + 3) * H2 + col0 + n4 * 4);
            #pragma unroll
            for (int j = 0; j < 4; ++j) {
                int n = n4 * 4 + j;
                ushort4 hv, lv;
                split1((&v0.x)[j], hv.x, lv.x);
                split1((&v1.x)[j], hv.y, lv.y);
                split1((&v2.x)[j], hv.z, lv.z);
                split1((&v3.x)[j], hv.w, lv.w);
                unsigned off = (unsigned)((n * 256 + kq * 8) ^ ((n & 7) << 4));
                *(ushort4*)((char*)Whi + off) = hv;
                *(ushort4*)((char*)Wlo + off) = lv;
            }
        }
        __syncthreads();
        // compute: wave wv covers k window [wv*32, wv*32+32) of this chunk
        unsigned bb = ((unsigned)((lane & 15) * 256) + kgb) ^ swz;
        bf16x8 bh = *(const bf16x8*)((char*)Whi + bb);
        bf16x8 bl = *(const bf16x8*)((char*)Wlo + bb);
        #pragma unroll
        for (int mt = 0; mt < 4; ++mt) {
            unsigned ab = ((unsigned)((mt * 16 + (lane & 15)) * 256) + kgb) ^ swz;
            bf16x8 ah = *(const bf16x8*)((char*)Xhi + ab);
            bf16x8 al = *(const bf16x8*)((char*)Xlo + ab);
            acc[mt] = __builtin_amdgcn_mfma_f32_16x16x32_bf16(ah, bh, acc[mt], 0, 0, 0);
            acc[mt] = __builtin_amdgcn_mfma_f32_16x16x32_bf16(ah, bl, acc[mt], 0, 0, 0);
            acc[mt] = __builtin_amdgcn_mfma_f32_16x16x32_bf16(al, bh, acc[mt], 0, 0, 0);
            acc[mt] = __builtin_amdgcn_mfma_f32_16x16x32_bf16(al, bl, acc[mt], 0, 0, 0);
        }
        __syncthreads();
    }
    // cross-wave reduce: red4[wave][row*16+col]
    #pragma unroll
    for (int mt = 0; mt < 4; ++mt) {
        int row = mt * 16 + (lane >> 4) * 4;
        #pragma unroll
        for (int reg = 0; reg < 4; ++reg)
            red4[wv * 1024 + (row + reg) * 16 + (lane & 15)] = acc[mt][reg];
    }
    __syncthreads();
    int row = t >> 2, cq = t & 3;
    const float4 s0 = *(const float4*)&red4[t * 4];
    const float4 s1 = *(const float4*)&red4[1024 + t * 4];
    const float4 s2 = *(const float4*)&red4[2048 + t * 4];
    const float4 s3 = *(const float4*)&red4[3072 + t * 4];
    float vout[4];
    #pragma unroll
    for (int j = 0; j < 4; ++j) {
        float v = (&s0.x)[j] + (&s1.x)[j] + (&s2.x)[j] + (&s3.x)[j]
                + ldT(bias, col0 + cq * 4 + j);
        vout[j] = v > 0.f ? v : SLOPE * v;
    }
    if (Ohi) {
        ushort4 hv, lv;
        split1(vout[0], hv.x, lv.x); split1(vout[1], hv.y, lv.y);
        split1(vout[2], hv.z, lv.z); split1(vout[3], hv.w, lv.w);
        *(ushort4*)&Ohi[(size_t)row * H2 + col0 + cq * 4] = hv;
        *(ushort4*)&Olo[(size_t)row * H2 + col0 + cq * 4] = lv;
    } else {
        float p = 0.f;
        #pragma unroll
        for (int j = 0; j < 4; ++j)
            p += vout[j] * ldT(ow, col0 + cq * 4 + j);
        red[cq * 64 + row] = p;
        __syncthreads();
        if (t < BB) {
            float s = red[t] + red[64 + t] + red[128 + t] + red[192 + t];
            atomicAdd(&outf[t], s);
            __threadfence();
            unsigned ticket = atomicAdd(&done[t], 1u);
            if (ticket == 47u) {
                __threadfence();
                float v = outf[t] + ldT(ob, 0);
                if (bf) ((__hip_bfloat16*)out)[t] = __float2bfloat16(v);
                else    ((float*)out)[t] = v;
            }
        }
    }
}

__global__ __launch_bounds__(256) void mlp_mfma2_kernel(
        const unsigned short* Xhi_g, const unsigned short* Xlo_g,
        const void* W, size_t woff, const void* bias, size_t boff,
        unsigned short* Ohi, unsigned short* Olo,
        const void* ow, const void* ob, float* outf, unsigned* done, void* out,
        const void* gamma) {
    __shared__ __align__(16) unsigned short Xhi[64 * 128];  // 16 KB
    __shared__ __align__(16) unsigned short Xlo[64 * 128];  // 16 KB
    __shared__ __align__(16) unsigned short Whi[16 * 128];  // 4 KB
    __shared__ __align__(16) unsigned short Wlo[16 * 128];  // 4 KB
    __shared__ float red4[4 * 1024];                        // 16 KB
    __shared__ float red[256];
    if (detect_bf(gamma))
        mlp_mfma2_body<__hip_bfloat16>(Xhi_g, Xlo_g,
                                       (const __hip_bfloat16*)W + woff,
                                       (const __hip_bfloat16*)bias + boff, Ohi, Olo,
                                       (const __hip_bfloat16*)ow, (const __hip_bfloat16*)ob,
                                       outf, done, out, 1,
                                       Xhi, Xlo, Whi, Wlo, red4, red);
    else
        mlp_mfma2_body<float>(Xhi_g, Xlo_g, (const float*)W + woff,
                              (const float*)bias + boff, Ohi, Olo,
                              (const float*)ow, (const float*)ob,
                              outf, done, out, 0,
                              Xhi, Xlo, Whi, Wlo, red4, red);
}

extern "C" void kernel_launch(void* const* d_in, const int* in_sizes, int n_in,
                              void* d_out, int out_size, void* d_ws, size_t ws_size,
                              hipStream_t stream) {
    const void* x_in = d_in[0];
    const void* c1w = d_in[2];  const void* c1b = d_in[3];
    const void* c2w = d_in[4];  const void* c2b = d_in[5];
    const void* c3w = d_in[6];  const void* c3b = d_in[7];
    const void* gam = d_in[8];  const void* bet = d_in[9];
    const void* lw  = d_in[10]; const void* lb  = d_in[11];
    const void* ow  = d_in[12]; const void* obb = d_in[13];

    char* w = (char*)d_ws;
    unsigned char* nbr = (unsigned char*)w;  w += (size_t)NN * KNN;
    float* t5a = (float*)w;                  w += (size_t)NN * FIN * 4;
    float* t5b = (float*)w;                  w += (size_t)NN * FIN * 4;
    float* bufA = (float*)w;                 w += (size_t)NN * HH * 4;
    float* bufB = (float*)w;                 w += (size_t)NN * HH * 4;
    float* bufC = (float*)w;                 w += (size_t)NN * HH * 4;
    float* bufD = (float*)w;                 w += (size_t)NN * HH * 4;
    float* g = (float*)w;                    w += (size_t)BB * H2 * 4;
    float* mA = (float*)w;                   w += (size_t)BB * H2 * 4;
    float* mB = (float*)w;                   w += (size_t)BB * H2 * 4;
    float* outf = (float*)w;                 w += (size_t)BB * 4;
    unsigned* done = (unsigned*)w;           w += (size_t)BB * 4;
    // Split activation buffers: mA/mB each hold exactly (hi,lo) u16 [64][768] pairs.
    unsigned short* Ahi = (unsigned short*)mA;
    unsigned short* Alo = Ahi + (size_t)BB * H2;
    unsigned short* Bhi = (unsigned short*)mB;
    unsigned short* Blo = Bhi + (size_t)BB * H2;

    float dinv = 1.0f / sqrtf((float)KNN);
    float nrm = dinv * dinv;

    knn_kernel<<<NN / 4, 256, 0, stream>>>(x_in, gam, nbr, g, outf, done);

    dim3 agg2_grid(BB, 4);
    dim3 tag_grid(NN / 64, 2);

    // ---- conv1 (Cin=5) ----
    agg5x2_kernel<<<BB, 256, 0, stream>>>(x_in, gam, nbr, t5a, t5b, nrm);
    tagmm5_kernel<<<NN / 16, 256, 0, stream>>>(x_in, t5a, t5b, c1w, c1b, bufA, g, gam);

    // ---- conv2: bufA -> bufD (+pool @256), fused 2-hop MFMA agg + MFMA tagmm ----
    agg2_mfma_kernel<<<agg2_grid, 256, 0, stream>>>(bufA, nbr, bufB, bufC, nrm);
    tagmm_mfma_kernel<<<tag_grid, 256, 0, stream>>>(bufA, bufB, bufC, c2w, c2b,
                                                    bufD, g, 256, gam);

    // ---- conv3: bufD -> bufC (+pool @512), fused 2-hop MFMA agg + MFMA tagmm ----
    agg2_mfma_kernel<<<agg2_grid, 256, 0, stream>>>(bufD, nbr, bufA, bufB, nrm);
    tagmm_mfma_kernel<<<tag_grid, 256, 0, stream>>>(bufD, bufA, bufB, c3w, c3b,
                                                    bufC, g, 512, gam);

    // ---- batchnorm (writes split activations) ----
    bn_split_kernel<<<6, 128, 0, stream>>>(g, gam, bet, Ahi, Alo);

    // ---- MLP: 5 MFMA layers on persistent split activations; last + fused dot ----
    mlp_mfma2_kernel<<<48, 256, 0, stream>>>(Ahi, Alo, lw, (size_t)0 * H2 * H2,
                                             lb, 0 * H2, Bhi, Blo,
                                             nullptr, nullptr, nullptr, nullptr,
                                             nullptr, gam);
    mlp_mfma2_kernel<<<48, 256, 0, stream>>>(Bhi, Blo, lw, (size_t)1 * H2 * H2,
                                             lb, 1 * H2, Ahi, Alo,
                                             nullptr, nullptr, nullptr, nullptr,
                                             nullptr, gam);
    mlp_mfma2_kernel<<<48, 256, 0, stream>>>(Ahi, Alo, lw, (size_t)2 * H2 * H2,
                                             lb, 2 * H2, Bhi, Blo,
                                             nullptr, nullptr, nullptr, nullptr,
                                             nullptr, gam);
    mlp_mfma2_kernel<<<48, 256, 0, stream>>>(Bhi, Blo, lw, (size_t)3 * H2 * H2,
                                             lb, 3 * H2, Ahi, Alo,
                                             nullptr, nullptr, nullptr, nullptr,
                                             nullptr, gam);
    mlp_mfma2_kernel<<<48, 256, 0, stream>>>(Ahi, Alo, lw, (size_t)4 * H2 * H2,
                                             lb, 4 * H2, nullptr, nullptr,
                                             ow, obb, outf, done, d_out, gam);
}

// Round 12
// 263.784 us; speedup vs baseline: 1.0164x; 1.0164x over previous
//
#include <hip/hip_runtime.h>
#include <hip/hip_bf16.h>
#include <math.h>

#define NN 16384
#define BB 64
#define NPG 256
#define KNN 100
#define FIN 5
#define HH 128
#define H2 768
#define SLOPE 0.01f

typedef __bf16 bf16x8 __attribute__((ext_vector_type(8)));
typedef float f32x4 __attribute__((ext_vector_type(4)));

// Inputs are fp32 (verified R3). Dtype detect inline: bn_gamma all-ones -> first 32 bits
// 0x3F800000 (fp32) vs 0x3F803F80 (bf16).
__device__ __forceinline__ int detect_bf(const void* gamma) {
    return ((const unsigned*)gamma)[0] == 0x3F803F80u;
}
__device__ __forceinline__ float loadin(const void* p, size_t i, int bf) {
    return bf ? __bfloat162float(((const __hip_bfloat16*)p)[i]) : ((const float*)p)[i];
}
template <typename T>
__device__ __forceinline__ float ldT(const T* p, size_t i) { return (float)p[i]; }
template <>
__device__ __forceinline__ float ldT<__hip_bfloat16>(const __hip_bfloat16* p, size_t i) {
    return __bfloat162float(p[i]);
}
__device__ __forceinline__ float4 ldT4(const float* p) { return *(const float4*)p; }
__device__ __forceinline__ float4 ldT4(const __hip_bfloat16* p) {
    ushort4 u = *(const ushort4*)p;
    return make_float4(__uint_as_float((unsigned)u.x << 16),
                       __uint_as_float((unsigned)u.y << 16),
                       __uint_as_float((unsigned)u.z << 16),
                       __uint_as_float((unsigned)u.w << 16));
}
__device__ __forceinline__ void stage_chunk(float* dst, const float* src, int n, int t) {
    const float4* s = (const float4*)src;
    float4* d = (float4*)dst;
    int n4 = n >> 2;
    for (int i = t; i < n4; i += 256) d[i] = s[i];
}
__device__ __forceinline__ void stage_chunk(float* dst, const __hip_bfloat16* src, int n, int t) {
    const ushort4* s = (const ushort4*)src;
    int n4 = n >> 2;
    for (int i = t; i < n4; i += 256) {
        ushort4 u = s[i];
        dst[i * 4 + 0] = __uint_as_float((unsigned)u.x << 16);
        dst[i * 4 + 1] = __uint_as_float((unsigned)u.y << 16);
        dst[i * 4 + 2] = __uint_as_float((unsigned)u.z << 16);
        dst[i * 4 + 3] = __uint_as_float((unsigned)u.w << 16);
    }
}

// Order-preserving fp32 <-> u32 map for atomicMax-based max pooling.
__device__ __forceinline__ unsigned enc_f(float f) {
    unsigned u = __float_as_uint(f);
    return (u & 0x80000000u) ? ~u : (u | 0x80000000u);
}
__device__ __forceinline__ float dec_f(unsigned u) {
    return __uint_as_float((u & 0x80000000u) ? (u & 0x7FFFFFFFu) : ~u);
}
// fp32 -> bf16 bits, round-to-nearest-even (finite values only)
__device__ __forceinline__ unsigned f2bf(float f) {
    unsigned u = __float_as_uint(f);
    unsigned r = 0x7fffu + ((u >> 16) & 1u);
    return (u + r) >> 16;
}
// split fp32 -> (hi = truncated bf16 bits [exact], lo = bf16(x - hi))
__device__ __forceinline__ void split1(float x, unsigned short& h, unsigned short& l) {
    unsigned u = __float_as_uint(x);
    unsigned hb = u & 0xFFFF0000u;
    h = (unsigned short)(hb >> 16);
    float rem = x - __uint_as_float(hb);     // exact in fp32
    l = (unsigned short)f2bf(rem);
}

// ---------------- KNN v7: radix-select top-100 (no sort, no LDS shuffles) ----------------
__global__ __launch_bounds__(256) void knn_kernel(const void* __restrict__ x_in,
                                                  const void* gamma,
                                                  unsigned char* __restrict__ nbr,
                                                  float* __restrict__ g,
                                                  float* __restrict__ outf,
                                                  unsigned* __restrict__ done) {
    int blk = blockIdx.x;
    int bf = detect_bf(gamma);
    int b = blk >> 6;
    int wave = threadIdx.x >> 6;
    int lane = threadIdx.x & 63;
    int il = ((blk & 63) << 2) + wave;
    {
        int gi = blk * 256 + threadIdx.x;
        if (blk < 192 && gi < BB * H2) {
            int cm = gi & 255;
            g[gi] = (cm < 128) ? 0.0f : __uint_as_float(0x007FFFFFu);
        }
        if (blk == 0 && threadIdx.x < BB) {
            outf[threadIdx.x] = 0.0f;
            done[threadIdx.x] = 0u;
        }
    }
    __shared__ float xg[FIN * NPG];   // transposed: xg[c*256 + node]
    for (int idx = threadIdx.x; idx < NPG * FIN; idx += 256) {
        int node = idx / FIN, c = idx - node * FIN;
        xg[c * NPG + node] = loadin(x_in, (size_t)b * NPG * FIN + idx, bf);
    }
    __syncthreads();
    float dq[4] = {0.f, 0.f, 0.f, 0.f};
    #pragma unroll
    for (int c = 0; c < FIN; ++c) {
        float xi = xg[c * NPG + il];                          // broadcast
        float4 xv = *(const float4*)&xg[c * NPG + lane * 4];  // conflict-free b128
        float d0 = xi - xv.x, d1 = xi - xv.y, d2 = xi - xv.z, d3 = xi - xv.w;
        dq[0] += d0 * d0; dq[1] += d1 * d1; dq[2] += d2 * d2; dq[3] += d3 * d3;
    }
    // keys: u32 distance bits (all positive -> uint order == float order); self = huge
    unsigned dk[4];
    #pragma unroll
    for (int q = 0; q < 4; ++q) {
        int e = lane * 4 + q;
        float dd = (e == il) ? 1e30f : dq[q];
        dk[q] = __float_as_uint(dd);
    }
    // binary search for T = 100th smallest value: max P with count(d < P) < 100
    unsigned P = 0;
    for (int bit = 30; bit >= 0; --bit) {
        unsigned cand = P | (1u << bit);
        int c = __popcll(__ballot(dk[0] < cand)) + __popcll(__ballot(dk[1] < cand))
              + __popcll(__ballot(dk[2] < cand)) + __popcll(__ballot(dk[3] < cand));
        if (c < KNN) P = cand;
    }
    // selection: all d<T, plus (KNN - n_less) of d==T by smallest index e=lane*4+q
    unsigned long long meq[4];
    int n_less = 0;
    #pragma unroll
    for (int q = 0; q < 4; ++q) {
        n_less += __popcll(__ballot(dk[q] < P));
        meq[q] = __ballot(dk[q] == P);
    }
    int quota = KNN - n_less;
    unsigned long long below = (1ull << lane) - 1ull;
    int run_eq = __popcll(meq[0] & below) + __popcll(meq[1] & below)
               + __popcll(meq[2] & below) + __popcll(meq[3] & below);
    bool sel[4];
    #pragma unroll
    for (int q = 0; q < 4; ++q) {
        int iseq = (int)((meq[q] >> lane) & 1ull);
        sel[q] = (dk[q] < P) || (iseq && run_eq < quota);
        run_eq += iseq;
    }
    unsigned long long msel[4];
    #pragma unroll
    for (int q = 0; q < 4; ++q) msel[q] = __ballot(sel[q]);
    int pos = __popcll(msel[0] & below) + __popcll(msel[1] & below)
            + __popcll(msel[2] & below) + __popcll(msel[3] & below);
    unsigned char* nb = &nbr[(size_t)(b * NPG + il) * KNN];
    #pragma unroll
    for (int q = 0; q < 4; ++q) {
        if (sel[q]) nb[pos] = (unsigned char)(lane * 4 + q);
        pos += sel[q] ? 1 : 0;
    }
}

// ---------------- aggregation, C=5, BOTH hops fused (x converted inline) ----------------
__global__ void agg5x2_kernel(const void* __restrict__ x_in, const void* gamma,
                              const unsigned char* __restrict__ nbr,
                              float* __restrict__ t5a, float* __restrict__ t5b, float nrm) {
    int b = blockIdx.x, i = threadIdx.x;
    int bf = detect_bf(gamma);
    __shared__ float xs[NPG * FIN];
    __shared__ float ys[NPG * FIN];
    for (int idx = threadIdx.x; idx < NPG * FIN; idx += 256)
        xs[idx] = loadin(x_in, (size_t)b * NPG * FIN + idx, bf);
    __syncthreads();
    const unsigned char* nb = nbr + (size_t)(b * NPG + i) * KNN;
    float a0=0.f, a1=0.f, a2=0.f, a3=0.f, a4=0.f;
    for (int k = 0; k < KNN; ++k) {
        int base = (int)nb[k] * FIN;
        a0 += xs[base+0]; a1 += xs[base+1]; a2 += xs[base+2];
        a3 += xs[base+3]; a4 += xs[base+4];
    }
    a0 *= nrm; a1 *= nrm; a2 *= nrm; a3 *= nrm; a4 *= nrm;
    size_t o = (size_t)(b * NPG + i) * FIN;
    t5a[o+0] = a0; t5a[o+1] = a1; t5a[o+2] = a2; t5a[o+3] = a3; t5a[o+4] = a4;
    ys[i*FIN+0] = a0; ys[i*FIN+1] = a1; ys[i*FIN+2] = a2;
    ys[i*FIN+3] = a3; ys[i*FIN+4] = a4;
    __syncthreads();
    a0=0.f; a1=0.f; a2=0.f; a3=0.f; a4=0.f;
    for (int k = 0; k < KNN; ++k) {
        int base = (int)nb[k] * FIN;
        a0 += ys[base+0]; a1 += ys[base+1]; a2 += ys[base+2];
        a3 += ys[base+3]; a4 += ys[base+4];
    }
    t5b[o+0] = nrm*a0; t5b[o+1] = nrm*a1; t5b[o+2] = nrm*a2;
    t5b[o+3] = nrm*a3; t5b[o+4] = nrm*a4;
}

// ---------------- aggregation, C=128, via MFMA: hop = nrm * (A x bf16(H)) ----------------
// Verified R2: frag layout A row=lane&15 k-contig; B col=lane&15; D col=lane&15,
// row=4*(lane>>4)+reg. XOR swizzle byte ^= (row&7)<<4 on 512B-stride rows.
// R6: Ht staging packs 4 nodes per ushort4 (b64) write.
__global__ __launch_bounds__(256) void agg_mfma_kernel(
        const float* __restrict__ hin, const unsigned char* __restrict__ nbr,
        float* __restrict__ hout, float nrm) {
    __shared__ __align__(16) unsigned short At[64 * 256];   // 32 KB
    __shared__ __align__(16) unsigned short Ht[64 * 256];   // 32 KB
    int t = threadIdx.x;
    int gph = blockIdx.x;
    int m0 = blockIdx.y * 64;        // node-row slice
    int c0 = blockIdx.z * 64;        // channel slice
    // zero A
    {
        uint4 zz = make_uint4(0u, 0u, 0u, 0u);
        uint4* za = (uint4*)At;
        #pragma unroll
        for (int i = 0; i < 8; ++i) za[t + i * 256] = zz;
    }
    __syncthreads();
    // stage H^T (bf16, swizzled): 4-node packed b64 writes
    for (int it = t; it < NPG * 4; it += 256) {   // nq = it>>4 (0..63), c4 = it&15
        int nq = it >> 4, c4 = it & 15;
        const float* src = &hin[((size_t)(gph * NPG + nq * 4)) * HH + c0 + c4 * 4];
        float4 v0 = *(const float4*)(src);
        float4 v1 = *(const float4*)(src + HH);
        float4 v2 = *(const float4*)(src + 2 * HH);
        float4 v3 = *(const float4*)(src + 3 * HH);
        #pragma unroll
        for (int j = 0; j < 4; ++j) {
            int c = c4 * 4 + j;
            ushort4 pk;
            pk.x = (unsigned short)f2bf((&v0.x)[j]);
            pk.y = (unsigned short)f2bf((&v1.x)[j]);
            pk.z = (unsigned short)f2bf((&v2.x)[j]);
            pk.w = (unsigned short)f2bf((&v3.x)[j]);
            unsigned off = (unsigned)((c * 512 + nq * 8) ^ ((c & 7) << 4));
            *(ushort4*)((char*)Ht + off) = pk;
        }
    }
    // scatter adjacency ones: row r = t>>2 (local), quarter q = t&3 (25 entries)
    {
        int r = t >> 2, q = t & 3;
        const unsigned char* nb = nbr + ((size_t)(gph * NPG + m0 + r)) * KNN + q * 25;
        unsigned rbase = (unsigned)(r * 512);
        unsigned rswz = (unsigned)((r & 7) << 4);
        for (int j = 0; j < 25; ++j) {
            int col = (int)nb[j];
            *(unsigned short*)((char*)At + ((rbase + col * 2) ^ rswz)) = 0x3F80u;
        }
    }
    __syncthreads();
    // MFMA: wave = one 16-row M-tile x 4 N-tiles, K = 256 in 8 steps of 32
    int wv = t >> 6, lane = t & 63;
    unsigned kgb = (unsigned)((lane >> 4) * 16);            // k-group byte offset
    unsigned swz = (unsigned)((lane & 7) << 4);
    unsigned abase = (unsigned)((wv * 16 + (lane & 15)) * 512) + kgb;
    f32x4 acc[4];
    #pragma unroll
    for (int nt = 0; nt < 4; ++nt) acc[nt] = (f32x4){0.f, 0.f, 0.f, 0.f};
    #pragma unroll
    for (int ks = 0; ks < 8; ++ks) {
        bf16x8 a = *(const bf16x8*)((char*)At + ((abase + ks * 64) ^ swz));
        #pragma unroll
        for (int nt = 0; nt < 4; ++nt) {
            unsigned bb = (unsigned)((nt * 16 + (lane & 15)) * 512) + kgb + ks * 64;
            bf16x8 bv = *(const bf16x8*)((char*)Ht + (bb ^ swz));
            acc[nt] = __builtin_amdgcn_mfma_f32_16x16x32_bf16(a, bv, acc[nt], 0, 0, 0);
        }
    }
    // epilogue: D row = (lane>>4)*4+reg, col = lane&15
    int rbase2 = m0 + wv * 16 + (lane >> 4) * 4;
    #pragma unroll
    for (int nt = 0; nt < 4; ++nt) {
        int col = c0 + nt * 16 + (lane & 15);
        #pragma unroll
        for (int reg = 0; reg < 4; ++reg) {
            int node = gph * NPG + rbase2 + reg;
            hout[(size_t)node * HH + col] = acc[nt][reg] * nrm;
        }
    }
}

// ---------------- pool epilogue (16-lane-group layout, used by tagmm5) ----------------
__device__ __forceinline__ void pool_epilogue(float* g, int b, int gc0, int cg, int rp,
                                              float* sv, float* mv) {
    #pragma unroll
    for (int mask = 1; mask < 16; mask <<= 1) {
        #pragma unroll
        for (int i = 0; i < 8; ++i) {
            sv[i] += __shfl_xor(sv[i], mask);
            mv[i] = fmaxf(mv[i], __shfl_xor(mv[i], mask));
        }
    }
    if (rp == 0) {
        #pragma unroll
        for (int i = 0; i < 8; ++i) {
            atomicAdd(&g[(size_t)b * H2 + gc0 + cg * 8 + i], sv[i]);
            atomicMax((unsigned*)&g[(size_t)b * H2 + gc0 + HH + cg * 8 + i], enc_f(mv[i]));
        }
    }
}

// ---------------- tagmm5 (+fused pool), X0 converted inline from raw x ----------------
template <typename T>
__device__ __forceinline__ void tagmm5_body(
        const T* __restrict__ X0raw, const float* __restrict__ X1,
        const float* __restrict__ X2,
        const T* __restrict__ W, const T* __restrict__ bias,
        float* __restrict__ O, float* g, float* Ws, float* Xs) {
    int t = threadIdx.x;
    int r0 = blockIdx.x * 16;
    int r = t & 15, cg = t >> 4;
    float acc[8] = {0.f,0.f,0.f,0.f,0.f,0.f,0.f,0.f};
    for (int h = 0; h < 3; ++h) {
        stage_chunk(Ws, W + (size_t)h * FIN * HH, FIN * HH, t);
        for (int idx = t; idx < 16 * FIN; idx += 256) {
            int rr = idx / FIN, k = idx - rr * FIN;
            size_t src = (size_t)(r0 + rr) * FIN + k;
            Xs[rr * 9 + k] = (h == 0) ? ldT(X0raw, src)
                           : (h == 1) ? X1[src] : X2[src];
        }
        __syncthreads();
        #pragma unroll
        for (int k = 0; k < FIN; ++k) {
            float xv = Xs[r * 9 + k];
            const float4 wa = *(const float4*)&Ws[k * HH + cg * 8];
            const float4 wb = *(const float4*)&Ws[k * HH + cg * 8 + 4];
            acc[0] += xv * wa.x; acc[1] += xv * wa.y;
            acc[2] += xv * wa.z; acc[3] += xv * wa.w;
            acc[4] += xv * wb.x; acc[5] += xv * wb.y;
            acc[6] += xv * wb.z; acc[7] += xv * wb.w;
        }
        __syncthreads();
    }
    size_t orow = (size_t)(r0 + r) * HH + cg * 8;
    float sv[8], mv[8];
    #pragma unroll
    for (int m = 0; m < 8; ++m) {
        float v = acc[m] + ldT(bias, cg * 8 + m);
        v = v > 0.f ? v : SLOPE * v;
        O[orow + m] = v;
        sv[m] = v * (1.0f / NPG);
        mv[m] = v;
    }
    pool_epilogue(g, r0 >> 8, 0, cg, r, sv, mv);
}

__global__ __launch_bounds__(256) void tagmm5_kernel(
        const void* X0raw, const float* X1, const float* X2,
        const void* W, const void* bias, float* O, float* g, const void* gamma) {
    __shared__ float Ws[FIN * HH];
    __shared__ float Xs[16 * 9];
    if (detect_bf(gamma))
        tagmm5_body<__hip_bfloat16>((const __hip_bfloat16*)X0raw, X1, X2,
                                    (const __hip_bfloat16*)W,
                                    (const __hip_bfloat16*)bias, O, g, Ws, Xs);
    else
        tagmm5_body<float>((const float*)X0raw, X1, X2, (const float*)W,
                           (const float*)bias, O, g, Ws, Xs);
}

// ---------------- tagmm128 via MFMA, 3-pass split-bf16 (+fused pool) ----------------
template <typename T>
__device__ __forceinline__ void tagmm_mfma_body(
        const float* __restrict__ X0, const float* __restrict__ X1,
        const float* __restrict__ X2,
        const T* __restrict__ W, const T* __restrict__ bias,
        float* __restrict__ O, float* g, int gcp,
        unsigned short* Xhi, unsigned short* Xlo,
        unsigned short* Whi, unsigned short* Wlo, float* pred) {
    int t = threadIdx.x;
    int m0 = blockIdx.x * 64;
    int gc0 = blockIdx.y * 64;
    int wv = t >> 6, lane = t & 63;
    const float* Xh[3] = {X0, X1, X2};
    f32x4 acc[4];
    #pragma unroll
    for (int nt = 0; nt < 4; ++nt) acc[nt] = (f32x4){0.f, 0.f, 0.f, 0.f};
    unsigned kgb = (unsigned)((lane >> 4) * 16);
    unsigned swz = (unsigned)((lane & 7) << 4);
    unsigned abase = (unsigned)((wv * 16 + (lane & 15)) * 256) + kgb;
    for (int h = 0; h < 3; ++h) {
        const float* X = Xh[h];
        for (int i = t; i < 2048; i += 256) {
            int row = i >> 5, c4 = i & 31;
            float4 v = *(const float4*)&X[(size_t)(m0 + row) * HH + c4 * 4];
            unsigned off = (unsigned)((row * 256 + c4 * 8) ^ ((row & 7) << 4));
            ushort4 h4, l4;
            split1(v.x, h4.x, l4.x); split1(v.y, h4.y, l4.y);
            split1(v.z, h4.z, l4.z); split1(v.w, h4.w, l4.w);
            *(ushort4*)((char*)Xhi + off) = h4;
            *(ushort4*)((char*)Xlo + off) = l4;
        }
        const T* Wg = W + ((size_t)h * HH) * HH + gc0;
        for (int i = t; i < 512; i += 256) {      // kq = i>>4 (0..31), n4 = i&15
            int kq = i >> 4, n4 = i & 15;
            int k0 = kq * 4;
            float4 v0 = ldT4(Wg + (size_t)(k0 + 0) * HH + n4 * 4);
            float4 v1 = ldT4(Wg + (size_t)(k0 + 1) * HH + n4 * 4);
            float4 v2 = ldT4(Wg + (size_t)(k0 + 2) * HH + n4 * 4);
            float4 v3 = ldT4(Wg + (size_t)(k0 + 3) * HH + n4 * 4);
            #pragma unroll
            for (int j = 0; j < 4; ++j) {
                int n = n4 * 4 + j;
                ushort4 hv, lv;
                split1((&v0.x)[j], hv.x, lv.x);
                split1((&v1.x)[j], hv.y, lv.y);
                split1((&v2.x)[j], hv.z, lv.z);
                split1((&v3.x)[j], hv.w, lv.w);
                unsigned off = (unsigned)((n * 256 + k0 * 2) ^ ((n & 7) << 4));
                *(ushort4*)((char*)Whi + off) = hv;
                *(ushort4*)((char*)Wlo + off) = lv;
            }
        }
        __syncthreads();
        #pragma unroll
        for (int ks = 0; ks < 4; ++ks) {
            bf16x8 ah = *(const bf16x8*)((char*)Xhi + ((abase + ks * 64) ^ swz));
            bf16x8 al = *(const bf16x8*)((char*)Xlo + ((abase + ks * 64) ^ swz));
            #pragma unroll
            for (int nt = 0; nt < 4; ++nt) {
                unsigned bb = ((unsigned)((nt * 16 + (lane & 15)) * 256) + kgb + ks * 64) ^ swz;
                bf16x8 bh = *(const bf16x8*)((char*)Whi + bb);
                bf16x8 bl = *(const bf16x8*)((char*)Wlo + bb);
                acc[nt] = __builtin_amdgcn_mfma_f32_16x16x32_bf16(ah, bh, acc[nt], 0, 0, 0);
                acc[nt] = __builtin_amdgcn_mfma_f32_16x16x32_bf16(ah, bl, acc[nt], 0, 0, 0);
                acc[nt] = __builtin_amdgcn_mfma_f32_16x16x32_bf16(al, bh, acc[nt], 0, 0, 0);
            }
        }
        __syncthreads();
    }
    int b = m0 >> 8;
    int grow0 = m0 + wv * 16 + (lane >> 4) * 4;
    float* psum = pred;            // [4][64]
    float* pmax = pred + 256;      // [4][64]
    #pragma unroll
    for (int nt = 0; nt < 4; ++nt) {
        int ncol = nt * 16 + (lane & 15);
        float bv = ldT(bias, gc0 + ncol);
        float cs = 0.f, cm = -INFINITY;
        #pragma unroll
        for (int reg = 0; reg < 4; ++reg) {
            float v = acc[nt][reg] + bv;
            v = v > 0.f ? v : SLOPE * v;
            O[(size_t)(grow0 + reg) * HH + gc0 + ncol] = v;
            cs += v;
            cm = fmaxf(cm, v);
        }
        cs += __shfl_xor(cs, 16); cs += __shfl_xor(cs, 32);
        cm = fmaxf(cm, __shfl_xor(cm, 16)); cm = fmaxf(cm, __shfl_xor(cm, 32));
        if (lane < 16) {
            psum[wv * 64 + ncol] = cs;
            pmax[wv * 64 + ncol] = cm;
        }
    }
    __syncthreads();
    if (t < 64) {
        float s = psum[t] + psum[64 + t] + psum[128 + t] + psum[192 + t];
        float m = fmaxf(fmaxf(pmax[t], pmax[64 + t]), fmaxf(pmax[128 + t], pmax[192 + t]));
        atomicAdd(&g[(size_t)b * H2 + gcp + gc0 + t], s * (1.0f / NPG));
        atomicMax((unsigned*)&g[(size_t)b * H2 + gcp + HH + gc0 + t], enc_f(m));
    }
}

__global__ __launch_bounds__(256) void tagmm_mfma_kernel(
        const float* X0, const float* X1, const float* X2,
        const void* W, const void* bias, float* O, float* g, int gcp, const void* gamma) {
    __shared__ __align__(16) unsigned short Xhi[64 * 128];  // 16 KB
    __shared__ __align__(16) unsigned short Xlo[64 * 128];
    __shared__ __align__(16) unsigned short Whi[64 * 128];  // [n][k]
    __shared__ __align__(16) unsigned short Wlo[64 * 128];
    __shared__ float pred[512];                             // psum[4][64] + pmax[4][64]
    if (detect_bf(gamma))
        tagmm_mfma_body<__hip_bfloat16>(X0, X1, X2, (const __hip_bfloat16*)W,
                                        (const __hip_bfloat16*)bias, O, g, gcp,
                                        Xhi, Xlo, Whi, Wlo, pred);
    else
        tagmm_mfma_body<float>(X0, X1, X2, (const float*)W, (const float*)bias,
                               O, g, gcp, Xhi, Xlo, Whi, Wlo, pred);
}

// ---------------- batchnorm: one-pass sum/sumsq; writes SPLIT (hi,lo) output ----------
__global__ void bn_split_kernel(const float* __restrict__ g, const void* gamma,
                                const void* beta, unsigned short* __restrict__ ghi,
                                unsigned short* __restrict__ glo) {
    int c = blockIdx.x * 128 + threadIdx.x;
    int bf = detect_bf(gamma);
    int ismax = (c & 255) >= 128;
    float s = 0.f, s2 = 0.f;
    #pragma unroll 8
    for (int b = 0; b < BB; ++b) {
        float raw = g[(size_t)b * H2 + c];
        float x = ismax ? dec_f(__float_as_uint(raw)) : raw;
        s += x; s2 += x * x;
    }
    float mu = s * (1.0f / BB);
    float var = fmaxf(s2 * (1.0f / BB) - mu * mu, 0.f);
    float rs = 1.0f / sqrtf(var + 1e-5f);
    float ga = loadin(gamma, c, bf), be = loadin(beta, c, bf);
    #pragma unroll 8
    for (int b = 0; b < BB; ++b) {
        float raw = g[(size_t)b * H2 + c];
        float x = ismax ? dec_f(__float_as_uint(raw)) : raw;
        float y = (x - mu) * rs * ga + be;
        unsigned short h, l;
        split1(y, h, l);
        ghi[(size_t)b * H2 + c] = h;
        glo[(size_t)b * H2 + c] = l;
    }
}

// ---------------- MLP layer via MFMA, persistent split-bf16 activations ----------------
template <typename T>
__device__ __forceinline__ void mlp_mfma2_body(
        const unsigned short* __restrict__ Xhi_g, const unsigned short* __restrict__ Xlo_g,
        const T* __restrict__ W, const T* __restrict__ bias,
        unsigned short* __restrict__ Ohi, unsigned short* __restrict__ Olo,
        const T* __restrict__ ow, const T* __restrict__ ob,
        float* __restrict__ outf, unsigned* __restrict__ done, void* out, int bf,
        unsigned short* Xhi, unsigned short* Xlo,
        unsigned short* Whi, unsigned short* Wlo, float* red4, float* red) {
    int t = threadIdx.x;
    int col0 = blockIdx.x * 16;
    int wv = t >> 6, lane = t & 63;
    f32x4 acc[4];
    #pragma unroll
    for (int mt = 0; mt < 4; ++mt) acc[mt] = (f32x4){0.f, 0.f, 0.f, 0.f};
    unsigned swz = (unsigned)((lane & 7) << 4);
    unsigned kgb = (unsigned)(wv * 64 + (lane >> 4) * 16);   // wave k-slice in 256B row
    for (int ch = 0; ch < 6; ++ch) {
        int k0 = ch * 128;
        // stage X chunk: pure b128 copies (global pre-split, same [row][k] layout)
        #pragma unroll
        for (int u = 0; u < 4; ++u) {
            int i = t + u * 256;
            int row = i >> 4, grp = i & 15;
            uint4 vh = *(const uint4*)&Xhi_g[(size_t)row * H2 + k0 + grp * 8];
            uint4 vl = *(const uint4*)&Xlo_g[(size_t)row * H2 + k0 + grp * 8];
            unsigned off = (unsigned)((row * 256 + grp * 16) ^ ((row & 7) << 4));
            *(uint4*)((char*)Xhi + off) = vh;
            *(uint4*)((char*)Xlo + off) = vl;
        }
        // stage W chunk transposed+split: [n][k], 128 items (kq x n4), 4-k packed b64
        if (t < 128) {
            int kq = t >> 2, n4 = t & 3;
            int kb = k0 + kq * 4;
            float4 v0 = ldT4(W + (size_t)(kb + 0) * H2 + col0 + n4 * 4);
            float4 v1 = ldT4(W + (size_t)(kb + 1) * H2 + col0 + n4 * 4);
            float4 v2 = ldT4(W + (size_t)(kb + 2) * H2 + col0 + n4 * 4);
            float4 v3 = ldT4(W + (size_t)(kb + 3) * H2 + col0 + n4 * 4);
            #pragma unroll
            for (int j = 0; j < 4; ++j) {
                int n = n4 * 4 + j;
                ushort4 hv, lv;
                split1((&v0.x)[j], hv.x, lv.x);
                split1((&v1.x)[j], hv.y, lv.y);
                split1((&v2.x)[j], hv.z, lv.z);
                split1((&v3.x)[j], hv.w, lv.w);
                unsigned off = (unsigned)((n * 256 + kq * 8) ^ ((n & 7) << 4));
                *(ushort4*)((char*)Whi + off) = hv;
                *(ushort4*)((char*)Wlo + off) = lv;
            }
        }
        __syncthreads();
        // compute: wave wv covers k window [wv*32, wv*32+32) of this chunk
        unsigned bb = ((unsigned)((lane & 15) * 256) + kgb) ^ swz;
        bf16x8 bh = *(const bf16x8*)((char*)Whi + bb);
        bf16x8 bl = *(const bf16x8*)((char*)Wlo + bb);
        #pragma unroll
        for (int mt = 0; mt < 4; ++mt) {
            unsigned ab = ((unsigned)((mt * 16 + (lane & 15)) * 256) + kgb) ^ swz;
            bf16x8 ah = *(const bf16x8*)((char*)Xhi + ab);
            bf16x8 al = *(const bf16x8*)((char*)Xlo + ab);
            acc[mt] = __builtin_amdgcn_mfma_f32_16x16x32_bf16(ah, bh, acc[mt], 0, 0, 0);
            acc[mt] = __builtin_amdgcn_mfma_f32_16x16x32_bf16(ah, bl, acc[mt], 0, 0, 0);
            acc[mt] = __builtin_amdgcn_mfma_f32_16x16x32_bf16(al, bh, acc[mt], 0, 0, 0);
            acc[mt] = __builtin_amdgcn_mfma_f32_16x16x32_bf16(al, bl, acc[mt], 0, 0, 0);
        }
        __syncthreads();
    }
    // cross-wave reduce: red4[wave][row*16+col]
    #pragma unroll
    for (int mt = 0; mt < 4; ++mt) {
        int row = mt * 16 + (lane >> 4) * 4;
        #pragma unroll
        for (int reg = 0; reg < 4; ++reg)
            red4[wv * 1024 + (row + reg) * 16 + (lane & 15)] = acc[mt][reg];
    }
    __syncthreads();
    int row = t >> 2, cq = t & 3;
    const float4 s0 = *(const float4*)&red4[t * 4];
    const float4 s1 = *(const float4*)&red4[1024 + t * 4];
    const float4 s2 = *(const float4*)&red4[2048 + t * 4];
    const float4 s3 = *(const float4*)&red4[3072 + t * 4];
    float vout[4];
    #pragma unroll
    for (int j = 0; j < 4; ++j) {
        float v = (&s0.x)[j] + (&s1.x)[j] + (&s2.x)[j] + (&s3.x)[j]
                + ldT(bias, col0 + cq * 4 + j);
        vout[j] = v > 0.f ? v : SLOPE * v;
    }
    if (Ohi) {
        ushort4 hv, lv;
        split1(vout[0], hv.x, lv.x); split1(vout[1], hv.y, lv.y);
        split1(vout[2], hv.z, lv.z); split1(vout[3], hv.w, lv.w);
        *(ushort4*)&Ohi[(size_t)row * H2 + col0 + cq * 4] = hv;
        *(ushort4*)&Olo[(size_t)row * H2 + col0 + cq * 4] = lv;
    } else {
        float p = 0.f;
        #pragma unroll
        for (int j = 0; j < 4; ++j)
            p += vout[j] * ldT(ow, col0 + cq * 4 + j);
        red[cq * 64 + row] = p;
        __syncthreads();
        if (t < BB) {
            float s = red[t] + red[64 + t] + red[128 + t] + red[192 + t];
            atomicAdd(&outf[t], s);
            __threadfence();
            unsigned ticket = atomicAdd(&done[t], 1u);
            if (ticket == 47u) {
                __threadfence();
                float v = outf[t] + ldT(ob, 0);
                if (bf) ((__hip_bfloat16*)out)[t] = __float2bfloat16(v);
                else    ((float*)out)[t] = v;
            }
        }
    }
}

__global__ __launch_bounds__(256) void mlp_mfma2_kernel(
        const unsigned short* Xhi_g, const unsigned short* Xlo_g,
        const void* W, size_t woff, const void* bias, size_t boff,
        unsigned short* Ohi, unsigned short* Olo,
        const void* ow, const void* ob, float* outf, unsigned* done, void* out,
        const void* gamma) {
    __shared__ __align__(16) unsigned short Xhi[64 * 128];  // 16 KB
    __shared__ __align__(16) unsigned short Xlo[64 * 128];  // 16 KB
    __shared__ __align__(16) unsigned short Whi[16 * 128];  // 4 KB
    __shared__ __align__(16) unsigned short Wlo[16 * 128];  // 4 KB
    __shared__ float red4[4 * 1024];                        // 16 KB
    __shared__ float red[256];
    if (detect_bf(gamma))
        mlp_mfma2_body<__hip_bfloat16>(Xhi_g, Xlo_g,
                                       (const __hip_bfloat16*)W + woff,
                                       (const __hip_bfloat16*)bias + boff, Ohi, Olo,
                                       (const __hip_bfloat16*)ow, (const __hip_bfloat16*)ob,
                                       outf, done, out, 1,
                                       Xhi, Xlo, Whi, Wlo, red4, red);
    else
        mlp_mfma2_body<float>(Xhi_g, Xlo_g, (const float*)W + woff,
                              (const float*)bias + boff, Ohi, Olo,
                              (const float*)ow, (const float*)ob,
                              outf, done, out, 0,
                              Xhi, Xlo, Whi, Wlo, red4, red);
}

extern "C" void kernel_launch(void* const* d_in, const int* in_sizes, int n_in,
                              void* d_out, int out_size, void* d_ws, size_t ws_size,
                              hipStream_t stream) {
    const void* x_in = d_in[0];
    const void* c1w = d_in[2];  const void* c1b = d_in[3];
    const void* c2w = d_in[4];  const void* c2b = d_in[5];
    const void* c3w = d_in[6];  const void* c3b = d_in[7];
    const void* gam = d_in[8];  const void* bet = d_in[9];
    const void* lw  = d_in[10]; const void* lb  = d_in[11];
    const void* ow  = d_in[12]; const void* obb = d_in[13];

    char* w = (char*)d_ws;
    unsigned char* nbr = (unsigned char*)w;  w += (size_t)NN * KNN;
    float* t5a = (float*)w;                  w += (size_t)NN * FIN * 4;
    float* t5b = (float*)w;                  w += (size_t)NN * FIN * 4;
    float* bufA = (float*)w;                 w += (size_t)NN * HH * 4;
    float* bufB = (float*)w;                 w += (size_t)NN * HH * 4;
    float* bufC = (float*)w;                 w += (size_t)NN * HH * 4;
    float* bufD = (float*)w;                 w += (size_t)NN * HH * 4;
    float* g = (float*)w;                    w += (size_t)BB * H2 * 4;
    float* mA = (float*)w;                   w += (size_t)BB * H2 * 4;
    float* mB = (float*)w;                   w += (size_t)BB * H2 * 4;
    float* outf = (float*)w;                 w += (size_t)BB * 4;
    unsigned* done = (unsigned*)w;           w += (size_t)BB * 4;
    // Split activation buffers: mA/mB each hold exactly (hi,lo) u16 [64][768] pairs.
    unsigned short* Ahi = (unsigned short*)mA;
    unsigned short* Alo = Ahi + (size_t)BB * H2;
    unsigned short* Bhi = (unsigned short*)mB;
    unsigned short* Blo = Bhi + (size_t)BB * H2;

    float dinv = 1.0f / sqrtf((float)KNN);
    float nrm = dinv * dinv;

    knn_kernel<<<NN / 4, 256, 0, stream>>>(x_in, gam, nbr, g, outf, done);

    dim3 aggm_grid(BB, 4, 2);
    dim3 tag_grid(NN / 64, 2);

    // ---- conv1 (Cin=5) ----
    agg5x2_kernel<<<BB, 256, 0, stream>>>(x_in, gam, nbr, t5a, t5b, nrm);
    tagmm5_kernel<<<NN / 16, 256, 0, stream>>>(x_in, t5a, t5b, c1w, c1b, bufA, g, gam);

    // ---- conv2: bufA -> bufD (+pool @256), MFMA agg + MFMA tagmm ----
    agg_mfma_kernel<<<aggm_grid, 256, 0, stream>>>(bufA, nbr, bufB, nrm);
    agg_mfma_kernel<<<aggm_grid, 256, 0, stream>>>(bufB, nbr, bufC, nrm);
    tagmm_mfma_kernel<<<tag_grid, 256, 0, stream>>>(bufA, bufB, bufC, c2w, c2b,
                                                    bufD, g, 256, gam);

    // ---- conv3: bufD -> bufC (+pool @512), MFMA agg + MFMA tagmm ----
    agg_mfma_kernel<<<aggm_grid, 256, 0, stream>>>(bufD, nbr, bufA, nrm);
    agg_mfma_kernel<<<aggm_grid, 256, 0, stream>>>(bufA, nbr, bufB, nrm);
    tagmm_mfma_kernel<<<tag_grid, 256, 0, stream>>>(bufD, bufA, bufB, c3w, c3b,
                                                    bufC, g, 512, gam);

    // ---- batchnorm (writes split activations) ----
    bn_split_kernel<<<6, 128, 0, stream>>>(g, gam, bet, Ahi, Alo);

    // ---- MLP: 5 MFMA layers on persistent split activations; last + fused dot ----
    mlp_mfma2_kernel<<<48, 256, 0, stream>>>(Ahi, Alo, lw, (size_t)0 * H2 * H2,
                                             lb, 0 * H2, Bhi, Blo,
                                             nullptr, nullptr, nullptr, nullptr,
                                             nullptr, gam);
    mlp_mfma2_kernel<<<48, 256, 0, stream>>>(Bhi, Blo, lw, (size_t)1 * H2 * H2,
                                             lb, 1 * H2, Ahi, Alo,
                                             nullptr, nullptr, nullptr, nullptr,
                                             nullptr, gam);
    mlp_mfma2_kernel<<<48, 256, 0, stream>>>(Ahi, Alo, lw, (size_t)2 * H2 * H2,
                                             lb, 2 * H2, Bhi, Blo,
                                             nullptr, nullptr, nullptr, nullptr,
                                             nullptr, gam);
    mlp_mfma2_kernel<<<48, 256, 0, stream>>>(Bhi, Blo, lw, (size_t)3 * H2 * H2,
                                             lb, 3 * H2, Ahi, Alo,
                                             nullptr, nullptr, nullptr, nullptr,
                                             nullptr, gam);
    mlp_mfma2_kernel<<<48, 256, 0, stream>>>(Ahi, Alo, lw, (size_t)4 * H2 * H2,
                                             lb, 4 * H2, nullptr, nullptr,
                                             ow, obb, outf, done, d_out, gam);
}